// Round 6
// baseline (288.585 us; speedup 1.0000x reference)
//
#include <hip/hip_runtime.h>
#include <hip/hip_bf16.h>
#include <stdint.h>

typedef __attribute__((ext_vector_type(8))) short bf16x8;
typedef __attribute__((ext_vector_type(4))) float f32x4;

#define BATCH 16
#define CH    256
#define HW    56
#define HWHW  3136   // 56*56
#define NK    8

// ---- workspace layout (bytes) ----
#define XPT_BYTES   30408704ul          // [16][58][64][256] bf16
#define WK_BYTES    18874368ul          // fragment-major: [b*9+kk][ci 8][frag 16][l15 16][g 4][e 8] bf16
#define POOL_BYTES  16384ul
#define ALPHA_BYTES 512ul

__device__ __forceinline__ void gl_lds16(const void* g, void* l) {
    __builtin_amdgcn_global_load_lds((const __attribute__((address_space(1))) uint32_t*)g,
                                     (__attribute__((address_space(3))) uint32_t*)l, 16, 0, 0);
}

__device__ __forceinline__ float bf16bits_to_f32(short h) {
    return __uint_as_float(((uint32_t)(uint16_t)h) << 16);
}

// ---------------- stage 1: fused transpose+pad+pool ----------------
// LDS swizzle: ch ^ ((x>>2)&7)<<3  -> store phase ~4-way conflict (was 14-way)
__global__ void __launch_bounds__(256, 2)
xpose_pool_kernel(const float* __restrict__ x, __hip_bfloat16* __restrict__ xp,
                  float* __restrict__ pooled) {
    __shared__ short tile[2 * 56 * 256];
    const int tid = threadIdx.x;
    const int ys  = blockIdx.x;            // 0..27
    const int b   = blockIdx.y;
    const int y0  = ys * 2;

    const float* xb = x + (size_t)b * CH * HWHW + (size_t)y0 * HW;
    for (int it = 0; it < 28; ++it) {
        int idx = it * 256 + tid;
        int ch  = idx / 28;
        int xi  = idx - ch * 28;
        int r   = xi / 14;
        int x4  = (xi - r * 14) * 4;
        const float4 v = *(const float4*)(xb + (size_t)ch * HWHW + r * HW + x4);
        const float* vf = (const float*)&v;
        int xr = ch ^ (((x4 >> 2) & 7) << 3);
#pragma unroll
        for (int j = 0; j < 4; ++j) {
            __hip_bfloat16 h = __float2bfloat16(vf[j]);
            tile[(r * 56 + x4 + j) * 256 + xr] = *(const short*)&h;
        }
    }
    __syncthreads();

    {
        float s = 0.f;
        const int ch = tid;
        for (int r = 0; r < 2; ++r)
            for (int xx = 0; xx < 56; ++xx)
                s += bf16bits_to_f32(tile[(r * 56 + xx) * 256 + (ch ^ (((xx >> 2) & 7) << 3))]);
        atomicAdd(&pooled[b * 256 + ch], s * (1.0f / 3136.0f));
    }

    __hip_bfloat16* dst0 = xp + ((size_t)(b * 58 + y0 + 1) * 64 + 1) * 256;
    for (int it = 0; it < 14; ++it) {
        int idx = it * 256 + tid;
        int ch0 = (idx & 31) * 8;
        int pos = idx >> 5;
        int r = pos / 56, xx = pos - (pos / 56) * 56;
        bf16x8 vv = *(const bf16x8*)&tile[(r * 56 + xx) * 256 + (ch0 ^ (((xx >> 2) & 7) << 3))];
        *(bf16x8*)(dst0 + ((size_t)(r * 64 + xx)) * 256 + ch0) = vv;
    }

    bf16x8 z = {};
    if (tid < 128) {
        int r   = tid >> 6;
        int c2  = (tid >> 5) & 1;
        int ch0 = (tid & 31) * 8;
        *(bf16x8*)(xp + ((size_t)(b * 58 + y0 + 1 + r) * 64 + (c2 ? 57 : 0)) * 256 + ch0) = z;
    }
    if (ys == 0 || ys == 27) {
        int p = (ys == 0) ? 0 : 57;
        __hip_bfloat16* rowp = xp + (size_t)(b * 58 + p) * 64 * 256;
        for (int it = tid; it < 2048; it += 256)
            *(bf16x8*)(rowp + (size_t)it * 8) = z;
    }
}

// ---------------- stage 2: MLP + softmax, one block per batch sample ----------------
__global__ void __launch_bounds__(256)
mlp_kernel(const float* __restrict__ pooled,
           const float* __restrict__ w1, const float* __restrict__ b1,
           const float* __restrict__ w2, const float* __restrict__ b2,
           float* __restrict__ alphas) {
    const int b = blockIdx.x;
    __shared__ float pl[256];
    __shared__ float hp[4][64];
    __shared__ float h[64];
    __shared__ float sc[8];
    int t = threadIdx.x;
    pl[t] = pooled[b * 256 + t];
    __syncthreads();
    int j = t & 63, part = t >> 6;
    float s = 0.f;
    const float* w1p = w1 + part * 64 * 64 + j;
#pragma unroll 8
    for (int c = 0; c < 64; ++c) s += pl[part * 64 + c] * w1p[c * 64];
    hp[part][j] = s;
    __syncthreads();
    if (t < 64) h[t] = fmaxf(hp[0][t] + hp[1][t] + hp[2][t] + hp[3][t] + b1[t], 0.f);
    __syncthreads();
    if (t < 8) {
        float acc = b2[t];
#pragma unroll 8
        for (int jj = 0; jj < 64; ++jj) acc += h[jj] * w2[jj * 8 + t];
        sc[t] = acc;
    }
    __syncthreads();
    if (t == 0) {
        float m = sc[0];
#pragma unroll
        for (int k = 1; k < 8; ++k) m = fmaxf(m, sc[k]);
        float ssum = 0.f, e[8];
#pragma unroll
        for (int k = 0; k < 8; ++k) { e[k] = expf(sc[k] - m); ssum += e[k]; }
        float inv = 1.0f / ssum;
#pragma unroll
        for (int k = 0; k < 8; ++k) alphas[b * 8 + k] = e[k] * inv;
    }
}

// ---------------- stage 3: mix kernels -> fragment-major wk ----------------
// wk byte addr for (b,q,o,i):
//   (b*9+q)*131072 + (i>>5)*16384 + (o>>4)*1024 + (o&15)*64 + ((i>>3)&3)*16 + (i&7)*2
__global__ void wmix_kernel(const float* __restrict__ kern, const float* __restrict__ alphas,
                            __hip_bfloat16* __restrict__ wk) {
    __shared__ float al[16][8];
    int t = threadIdx.x;
    if (t < 128) al[t >> 3][t & 7] = alphas[t];
    __syncthreads();
    const int o = blockIdx.x, i = t;
    const int idx = o * 256 + i;
    const size_t ibase = (size_t)((i >> 5) * 16384 + ((o >> 4)) * 1024 + (o & 15) * 64 +
                                  ((i >> 3) & 3) * 16 + (i & 7) * 2);
    float kv[8][9];
    const float* kp = kern + (size_t)idx * 9;
#pragma unroll
    for (int k = 0; k < 8; ++k)
#pragma unroll
        for (int q = 0; q < 9; ++q) kv[k][q] = kp[(size_t)k * 589824 + q];
    char* wkb = (char*)wk;
#pragma unroll 1
    for (int b = 0; b < 16; ++b) {
#pragma unroll
        for (int q = 0; q < 9; ++q) {
            float acc = 0.f;
#pragma unroll
            for (int k = 0; k < 8; ++k) acc += al[b][k] * kv[k][q];
            __hip_bfloat16 h = __float2bfloat16(acc);
            *(short*)(wkb + (size_t)(b * 9 + q) * 131072 + ibase) = *(const short*)&h;
        }
    }
}

// ---------------- stage 4: conv — 8 waves/block for TLP, 8 barriers total ----------------
// flat grid 448 (XCD-chunked swizzle), block 512 (8 waves = 4M x 2N), all blocks co-resident
// BM=128, BN=224 = 4 out-rows x 56; per wave fm=2, fn=7
__global__ void __launch_bounds__(512, 4)
conv_kernel(const __hip_bfloat16* __restrict__ xpT, const __hip_bfloat16* __restrict__ wk,
            float* __restrict__ out) {
    __shared__ short lds_x[2][6 * 64 * 32];   // 2 x 24KB

    const int tid   = threadIdx.x;
    const int lane  = tid & 63;
    const int g     = lane >> 4;
    const int l15   = lane & 15;
    const int w     = tid >> 6;            // 0..7
    const int wm    = w >> 1;              // 0..3 (M)
    const int wn    = w & 1;               // 0..1 (N)
    const int w64   = tid & ~63;

    const int flat  = blockIdx.x;
    const int swzid = (flat & 7) * 56 + (flat >> 3);
    const int b     = swzid / 28;
    const int rem   = swzid - b * 28;
    const int mtile = rem & 1;
    const int y0    = (rem >> 1) * 4;

    int cellb[7];
#pragma unroll
    for (int fn = 0; fn < 7; ++fn) {
        int n = wn * 112 + fn * 16 + l15;
        cellb[fn] = (n / 56) * 64 + (n % 56);
    }

    f32x4 acc[2][7];
#pragma unroll
    for (int fm = 0; fm < 2; ++fm)
#pragma unroll
        for (int fn = 0; fn < 7; ++fn) acc[fm][fn] = (f32x4){0.f, 0.f, 0.f, 0.f};

    const size_t xb = ((size_t)b * 58 + y0) * 64 * 256;
    // wave covers o-frags mtile*8 + wm*2 + {0,1}
    const char* wkb = (const char*)wk + (size_t)(b * 9) * 131072 +
                      (size_t)((mtile * 8 + wm * 2) * 1024 + l15 * 64 + g * 16);

#define STAGE_X(CI, BUF)                                                            \
    do {                                                                            \
        _Pragma("unroll")                                                           \
        for (int it = 0; it < 3; ++it) {                                            \
            int idx = it * 512 + tid;                                               \
            int sg  = idx & 3, cell = idx >> 2;                                     \
            int c = cell & 63;                                                      \
            int h = sg ^ ((c >> 1) & 3);                                            \
            const __hip_bfloat16* src = xpT + xb + (size_t)cell * 256 + (CI) * 32 + h * 8; \
            gl_lds16(src, (char*)lds_x[BUF] + (it * 512 + w64) * 16);               \
        }                                                                           \
    } while (0)

#define LOADA(KK, AR)                                                               \
    do {                                                                            \
        _Pragma("unroll")                                                           \
        for (int fm = 0; fm < 2; ++fm)                                              \
            AR[fm] = *(const bf16x8*)(wkb + (size_t)((KK) * 131072 + ci * 16384 + fm * 1024)); \
    } while (0)

#define STEPB(KK, AR)                                                               \
    do {                                                                            \
        const int kh = (KK) / 3, kw = (KK) % 3;                                     \
        bf16x8 bf[7];                                                               \
        _Pragma("unroll")                                                           \
        for (int fn = 0; fn < 7; ++fn) {                                            \
            int cell = cellb[fn] + kh * 64 + kw;                                    \
            int slot = g ^ ((((cellb[fn] & 63) + kw) >> 1) & 3);                    \
            bf[fn] = *(const bf16x8*)(xlds + cell * 64 + (slot << 4));              \
        }                                                                           \
        __builtin_amdgcn_s_setprio(1);                                              \
        _Pragma("unroll")                                                           \
        for (int fn = 0; fn < 7; ++fn)                                              \
            _Pragma("unroll")                                                       \
            for (int fm = 0; fm < 2; ++fm)                                          \
                acc[fm][fn] = __builtin_amdgcn_mfma_f32_16x16x32_bf16(AR[fm], bf[fn], acc[fm][fn], 0, 0, 0); \
        __builtin_amdgcn_s_setprio(0);                                              \
    } while (0)

    STAGE_X(0, 0);
    __syncthreads();

#pragma unroll 1
    for (int ci = 0; ci < 8; ++ci) {
        const char* xlds = (const char*)lds_x[ci & 1];
        bf16x8 afA[2], afB[2];
        LOADA(0, afA);
        if (ci < 7) STAGE_X(ci + 1, (ci & 1) ^ 1);   // async, overlaps whole chunk
        LOADA(1, afB);
        STEPB(0, afA); LOADA(2, afA);
        STEPB(1, afB); LOADA(3, afB);
        STEPB(2, afA); LOADA(4, afA);
        STEPB(3, afB); LOADA(5, afB);
        STEPB(4, afA); LOADA(6, afA);
        STEPB(5, afB); LOADA(7, afB);
        STEPB(6, afA); LOADA(8, afA);
        STEPB(7, afB);
        STEPB(8, afA);
        if (ci < 7) __syncthreads();                  // single barrier per chunk
    }

    // epilogue: C/D layout col=l15, row=4*g+reg
    const int mbase = mtile * 128 + wm * 32;
#pragma unroll
    for (int fm = 0; fm < 2; ++fm)
#pragma unroll
        for (int fn = 0; fn < 7; ++fn) {
            int n = wn * 112 + fn * 16 + l15;
            int r = n / 56, c = n - (n / 56) * 56;
            int o = mbase + fm * 16 + 4 * g;
            float* op = out + (((size_t)b * 256 + o) * 56 + (y0 + r)) * 56 + c;
#pragma unroll
            for (int q = 0; q < 4; ++q) op[(size_t)q * HWHW] = acc[fm][fn][q];
        }
#undef STAGE_X
#undef LOADA
#undef STEPB
}

extern "C" void kernel_launch(void* const* d_in, const int* in_sizes, int n_in,
                              void* d_out, int out_size, void* d_ws, size_t ws_size,
                              hipStream_t stream) {
    const float* x    = (const float*)d_in[0];
    const float* kern = (const float*)d_in[1];
    const float* w1   = (const float*)d_in[2];
    const float* b1   = (const float*)d_in[3];
    const float* w2   = (const float*)d_in[4];
    const float* b2   = (const float*)d_in[5];
    float* out = (float*)d_out;

    char* wsp = (char*)d_ws;
    __hip_bfloat16* xpT    = (__hip_bfloat16*)wsp;
    __hip_bfloat16* wkbuf  = (__hip_bfloat16*)(wsp + XPT_BYTES);
    float*          pooled = (float*)(wsp + XPT_BYTES + WK_BYTES);
    float*          alphas = (float*)(wsp + XPT_BYTES + WK_BYTES + POOL_BYTES);

    hipMemsetAsync(pooled, 0, POOL_BYTES, stream);

    xpose_pool_kernel<<<dim3(28, 16), dim3(256), 0, stream>>>(x, xpT, pooled);
    mlp_kernel<<<dim3(16), dim3(256), 0, stream>>>(pooled, w1, b1, w2, b2, alphas);
    wmix_kernel<<<dim3(256), dim3(256), 0, stream>>>(kern, alphas, wkbuf);
    conv_kernel<<<dim3(448), dim3(512), 0, stream>>>(xpT, wkbuf, out);
}